// Round 1
// baseline (848.222 us; speedup 1.0000x reference)
//
#include <hip/hip_runtime.h>

typedef unsigned char u8;

#define TT 1024
#define BB 512
#define LL 50
#define STOPI 48
#define STARTI 49
#define NEGV -10000.0f

// ws layout:
//   [0, 2048)                : int idx[512]   (argmax of final vit per batch)
//   [4096, 4096 + B*T*50)    : u8 ptr[B][T][50]  backpointers

__global__ __launch_bounds__(256) void viterbi_fwd(
    const float* __restrict__ feats, const int* __restrict__ lens,
    const float* __restrict__ trans, float* __restrict__ out_scores,
    int* __restrict__ idx_ws, u8* __restrict__ ptr_ws)
{
    const int b   = blockIdx.x;
    const int tid = threadIdx.x;
    const int to  = tid & 63;        // target label this thread owns
    const int q   = tid >> 6;        // wave id: splits the 'from' dimension
    const int fstart = q * 12;       // q0:[0,12) q1:[12,24) q2:[24,36) q3:[36,50)
    const int cnt    = (q == 3) ? 14 : 12;

    __shared__ __align__(16) float vit[64];
    __shared__ float pbest[4][64];
    __shared__ int   pidx[4][64];
    __shared__ u8    rowbuf[64];

    // transitions for this thread's (to, from-range) -> registers, loaded once
    float trr[14];
#pragma unroll
    for (int j = 0; j < 14; ++j) {
        trr[j] = (to < LL && j < cnt) ? trans[to * LL + fstart + j] : 0.0f;
    }
    const float tr_stop = (to < LL) ? trans[STOPI * LL + to] : 0.0f;

    const int len = lens[b];

    if (tid < 64) vit[tid] = (tid == STARTI) ? 0.0f : NEGV;
    __syncthreads();

    const float* fb = feats + (size_t)b * TT * LL;
    u8* pb = ptr_ws + (size_t)b * TT * LL;

    // partial max-plus argmax over this thread's from-range (strict > => first index wins)
    auto partial = [&](float& best, int& bi) {
        float vv[12];
        {
            const float4* vp = (const float4*)&vit[fstart];
            float4 a = vp[0], b4 = vp[1], c4 = vp[2];
            vv[0] = a.x;  vv[1] = a.y;  vv[2] = a.z;  vv[3] = a.w;
            vv[4] = b4.x; vv[5] = b4.y; vv[6] = b4.z; vv[7] = b4.w;
            vv[8] = c4.x; vv[9] = c4.y; vv[10] = c4.z; vv[11] = c4.w;
        }
        best = -3.4e38f; bi = fstart;
#pragma unroll
        for (int j = 0; j < 12; ++j) {
            float s = vv[j] + trr[j];
            if (s > best) { best = s; bi = fstart + j; }
        }
        if (q == 3) {
            float s = vit[48] + trr[12];
            if (s > best) { best = s; bi = 48; }
            s = vit[49] + trr[13];
            if (s > best) { best = s; bi = 49; }
        }
    };

    // feats prefetch, 2 rows deep (only wave 0 lanes <50 consume feats)
    float fc0 = 0.f, fc1 = 0.f;
    if (q == 0 && to < LL) {
        fc0 = fb[0 * LL + to];
        fc1 = fb[1 * LL + to];
    }

    for (int t = 0; t < len; ++t) {
        float fc2 = 0.f;
        if (q == 0 && to < LL) {
            int t2 = t + 2; if (t2 > TT - 1) t2 = TT - 1;
            fc2 = fb[(size_t)t2 * LL + to];
        }
        float best; int bi;
        partial(best, bi);
        pbest[q][to] = best; pidx[q][to] = bi;
        __syncthreads();
        if (q == 0 && to < LL) {
            // combine in q order with strict > : preserves global first-index argmax
            float B0 = pbest[0][to]; int I0 = pidx[0][to];
            float B1 = pbest[1][to]; int I1 = pidx[1][to];
            if (B1 > B0) { B0 = B1; I0 = I1; }
            float B2 = pbest[2][to]; int I2 = pidx[2][to];
            if (B2 > B0) { B0 = B2; I0 = I2; }
            float B3 = pbest[3][to]; int I3 = pidx[3][to];
            if (B3 > B0) { B0 = B3; I0 = I3; }
            pb[(size_t)t * LL + to] = (u8)I0;
            float nv = B0 + fc0;              // c>0 guaranteed (t<len)
            if (t == len - 1) nv += tr_stop;  // c==1 exactly at last real step
            vit[to] = nv;
        }
        fc0 = fc1; fc1 = fc2;
        __syncthreads();
    }

    // final (frozen) ptr row: ptr[t] for all t in [len, T) are identical
    {
        float best; int bi;
        partial(best, bi);
        pbest[q][to] = best; pidx[q][to] = bi;
    }
    __syncthreads();
    if (q == 0 && to < LL) {
        float B0 = pbest[0][to]; int I0 = pidx[0][to];
        float B1 = pbest[1][to]; int I1 = pidx[1][to];
        if (B1 > B0) { B0 = B1; I0 = I1; }
        float B2 = pbest[2][to]; int I2 = pidx[2][to];
        if (B2 > B0) { B0 = B2; I0 = I2; }
        float B3 = pbest[3][to]; int I3 = pidx[3][to];
        if (B3 > B0) { B0 = B3; I0 = I3; }
        rowbuf[to] = (u8)I0;
    }
    __syncthreads();

    // fill ptr rows for t in [len, T) with the constant row (50-byte period;
    // region starts at a multiple of 50 so phase of element i is i % 50)
    {
        const int total = (TT - len) * LL;
        u8* base = pb + (size_t)len * LL;
        int r = tid % 50;
        for (int i = tid; i < total; i += 256) {
            base[i] = rowbuf[r];
            r += 6; if (r >= 50) r -= 50;   // (i+256) % 50 advance
        }
    }
    __syncthreads();

    if (tid == 0) {
        float best = vit[0]; int bi = 0;
        for (int l = 1; l < LL; ++l) {
            if (vit[l] > best) { best = vit[l]; bi = l; }
        }
        out_scores[b] = best;
        idx_ws[b] = bi;
    }
}

// Backtrack with chunked pointer-jumping: 32 chunks x 32 steps.
__global__ __launch_bounds__(64) void viterbi_bwd(
    const int* __restrict__ idx_ws, const u8* __restrict__ ptr_ws,
    float* __restrict__ out_paths)
{
    const int b = blockIdx.x;
    const int lane = threadIdx.x;

    __shared__ u8 lptr[TT * LL];    // 51200 B
    __shared__ u8 maps[32 * LL];    // chunk maps: maps[c*50 + entry] = exit state
    __shared__ int entries[33];     // entries[c+1] = state entering chunk c from the right

    // stage this batch's ptr slab into LDS (coalesced 16B loads)
    {
        const uint4* src = (const uint4*)(ptr_ws + (size_t)b * TT * LL);
        uint4* dst = (uint4*)lptr;
        for (int i = lane; i < (TT * LL) / 16; i += 64) dst[i] = src[i];
    }
    __syncthreads();

    // phase 1: all 1600 (chunk, entry) walks; 25 independent chains per lane
    {
        int st[25], tb[25], cidx[25];
#pragma unroll
        for (int k = 0; k < 25; ++k) {
            int w = k * 64 + lane;       // 0..1599
            int c = w / 50;
            int l = w - c * 50;
            st[k] = l;
            tb[k] = (c * 32 + 31) * 50;  // byte row of last t in chunk
            cidx[k] = c * 50 + l;
        }
        for (int j = 0; j < 32; ++j) {
#pragma unroll
            for (int k = 0; k < 25; ++k) {
                st[k] = lptr[tb[k] + st[k]];
                tb[k] -= 50;
            }
        }
#pragma unroll
        for (int k = 0; k < 25; ++k) maps[cidx[k]] = (u8)st[k];
    }
    __syncthreads();

    const int idx = idx_ws[b];

    // phase 2: compose chunk maps sequentially (32 dependent LDS reads)
    if (lane == 0) {
        int i = idx;
        for (int c = 31; c >= 0; --c) {
            entries[c + 1] = i;
            i = maps[c * 50 + i];
        }
        entries[0] = i;
    }
    __syncthreads();

    // phase 3: re-walk all 32 chunks in parallel, writing the path
    float* po = out_paths + (size_t)b * TT;
    if (lane < 32) {
        const int c = lane;
        int s = entries[c + 1];
        int tbase = (c * 32 + 31) * 50;
        for (int j = 0; j < 32; ++j) {
            int t = c * 32 + 31 - j;
            int ni = lptr[tbase + s];
            tbase -= 50;
            if (t > 0) po[t - 1] = (float)ni;   // paths[t-1] = back_seq[t]
            s = ni;
        }
    }
    if (lane == 0) po[TT - 1] = (float)idx;     // paths[T-1] = argmax(vit)
}

extern "C" void kernel_launch(void* const* d_in, const int* in_sizes, int n_in,
                              void* d_out, int out_size, void* d_ws, size_t ws_size,
                              hipStream_t stream) {
    const float* feats = (const float*)d_in[0];
    const int*   lens  = (const int*)d_in[1];
    const float* trans = (const float*)d_in[2];

    float* scores = (float*)d_out;          // [512]
    float* paths  = scores + BB;            // [512*1024] (ints stored as floats)

    int* idx_ws = (int*)d_ws;
    u8*  ptr_ws = (u8*)d_ws + 4096;

    viterbi_fwd<<<BB, 256, 0, stream>>>(feats, lens, trans, scores, idx_ws, ptr_ws);
    viterbi_bwd<<<BB, 64, 0, stream>>>(idx_ws, ptr_ws, paths);
}

// Round 2
// 703.327 us; speedup vs baseline: 1.2060x; 1.2060x over previous
//
#include <hip/hip_runtime.h>

typedef unsigned char u8;

#define TT 1024
#define BB 512
#define LL 50
#define STOPI 48
#define STARTI 49
#define NEGV -10000.0f

// ws layout:
//   [0, 2048)             : int idx[512]   (argmax of final vit per batch)
//   [4096, 4096+B*50*T)   : u8 ptr[B][50][T]  backpointers, TRANSPOSED [label][time]

// Single wave per batch. No __syncthreads anywhere in the hot loop:
// vit broadcast via v_readlane, feats staged via LDS one chunk ahead,
// backpointers packed 4/dword and stored fire-and-forget.
__global__ __launch_bounds__(64) void viterbi_fwd(
    const float* __restrict__ feats, const int* __restrict__ lens,
    const float* __restrict__ trans, float* __restrict__ out_scores,
    int* __restrict__ idx_ws, u8* __restrict__ ptr_ws)
{
    const int b    = blockIdx.x;
    const int lane = threadIdx.x;          // 0..63; lane == 'to' label
    const int row  = (lane < LL) ? lane : (LL - 1);   // clamp for OOB-safe setup

    // transitions row for this 'to' -> 50 VGPRs (one-time, L2-cached)
    float trr[LL];
#pragma unroll
    for (int j = 0; j < LL; ++j) trr[j] = trans[row * LL + j];
    const float tr_stop = trans[STOPI * LL + row];

    const int len = lens[b];
    const int nchunks = (len + 15) >> 4;   // 16-step chunks with real work

    float vit = (lane == STARTI) ? 0.0f : NEGV;

    __shared__ float featbuf[1024];        // 16 rows x 50 floats, padded to 1024

    const float* fb = feats + (size_t)b * (TT * LL);
    u8* pt = ptr_ws + (size_t)b * (TT * LL) + (size_t)row * TT;  // [to][t]

    // prefetch chunk 0 into registers (4 x float4 per lane covers 800 floats)
    float4 nf0, nf1, nf2, nf3;
    {
        const float4* s4 = (const float4*)fb;
        const int i3 = (lane + 192 > 199) ? 199 : lane + 192;
        nf0 = s4[lane]; nf1 = s4[lane + 64]; nf2 = s4[lane + 128]; nf3 = s4[i3];
    }

    // streaming 4-chain argmax over from in [0,50); contiguous blocks so the
    // chain-combine in block order with strict > preserves first-index ties.
#define SCAN_BLOCK(J0, J1, BST, IDX)                                          \
    {                                                                          \
        _Pragma("unroll")                                                      \
        for (int j = (J0); j < (J1); ++j) {                                    \
            float s = __int_as_float(                                          \
                          __builtin_amdgcn_readlane(__float_as_int(vit), j))   \
                      + trr[j];                                                \
            if (s > (BST)) { (BST) = s; (IDX) = j; }                           \
        }                                                                      \
    }

    unsigned pk = 0;
    for (int c = 0; c < nchunks; ++c) {
        // stage chunk c (registers -> LDS); single wave => in-order DS, no barrier
        float4* f4 = (float4*)featbuf;
        f4[lane] = nf0; f4[lane + 64] = nf1; f4[lane + 128] = nf2; f4[lane + 192] = nf3;

        // prefetch chunk c+1 (vmcnt waited ~16 steps from now, fully hidden)
        {
            const int cn = (c + 1 > 63) ? 63 : c + 1;
            const float4* s4 = (const float4*)(fb + cn * 800);
            const int i3 = (lane + 192 > 199) ? 199 : lane + 192;
            nf0 = s4[lane]; nf1 = s4[lane + 64]; nf2 = s4[lane + 128]; nf3 = s4[i3];
        }

        for (int i = 0; i < 16; ++i) {
            const int t = (c << 4) + i;
            const float f = featbuf[i * 50 + lane];   // issued early, indep of vit

            float b0 = -3.4e38f, b1 = -3.4e38f, b2 = -3.4e38f, b3 = -3.4e38f;
            int   i0 = 0, i1 = 13, i2 = 26, i3 = 39;
            SCAN_BLOCK(0, 13, b0, i0)
            SCAN_BLOCK(13, 26, b1, i1)
            SCAN_BLOCK(26, 39, b2, i2)
            SCAN_BLOCK(39, 50, b3, i3)
            if (b1 > b0) { b0 = b1; i0 = i1; }
            if (b2 > b0) { b0 = b2; i0 = i2; }
            if (b3 > b0) { b0 = b3; i0 = i3; }

            pk = (pk >> 8) | ((unsigned)i0 << 24);    // byte (t&3) == idx at t
            if ((t & 3) == 3 && lane < LL)
                *(unsigned*)(pt + t - 3) = pk;        // fire-and-forget

            if (t < len) {                            // wave-uniform branch
                float nv = b0 + f;
                if (t == len - 1) nv += tr_stop;
                vit = nv;
            }
        }
    }

    // frozen row for t >= nchunks*16 (vit no longer changes)
    {
        float b0 = -3.4e38f, b1 = -3.4e38f, b2 = -3.4e38f, b3 = -3.4e38f;
        int   i0 = 0, i1 = 13, i2 = 26, i3 = 39;
        SCAN_BLOCK(0, 13, b0, i0)
        SCAN_BLOCK(13, 26, b1, i1)
        SCAN_BLOCK(26, 39, b2, i2)
        SCAN_BLOCK(39, 50, b3, i3)
        if (b1 > b0) { b0 = b1; i0 = i1; }
        if (b2 > b0) { b0 = b2; i0 = i2; }
        if (b3 > b0) { b0 = b3; i0 = i3; }

        const unsigned pat = (unsigned)i0 * 0x01010101u;
        uint4 q; q.x = pat; q.y = pat; q.z = pat; q.w = pat;
        if (lane < LL)
            for (int c2 = nchunks; c2 < 64; ++c2)
                *(uint4*)(pt + (c2 << 4)) = q;
    }

    // final score / argmax over vit[0..49] (single chain, first-index)
    {
        float m = -3.4e38f; int mi = 0;
#pragma unroll
        for (int j = 0; j < LL; ++j) {
            float s = __int_as_float(__builtin_amdgcn_readlane(__float_as_int(vit), j));
            if (s > m) { m = s; mi = j; }
        }
        if (lane == 0) { out_scores[b] = m; idx_ws[b] = mi; }
    }
#undef SCAN_BLOCK
}

// Backtrack with chunked pointer-jumping: 32 chunks x 32 steps.
// ptr layout is transposed: lptr[label*1024 + t].
__global__ __launch_bounds__(64) void viterbi_bwd(
    const int* __restrict__ idx_ws, const u8* __restrict__ ptr_ws,
    float* __restrict__ out_paths)
{
    const int b = blockIdx.x;
    const int lane = threadIdx.x;

    __shared__ u8 lptr[TT * LL];    // 51200 B, [label][t]
    __shared__ u8 maps[32 * LL];    // maps[c*50 + entry] = exit state of chunk c
    __shared__ int entries[33];

    {
        const uint4* src = (const uint4*)(ptr_ws + (size_t)b * TT * LL);
        uint4* dst = (uint4*)lptr;
        for (int i = lane; i < (TT * LL) / 16; i += 64) dst[i] = src[i];
    }
    __syncthreads();

    // phase 1: all 1600 (chunk, entry) walks; 25 independent chains per lane
    {
        int st[25], tt[25], cidx[25];
#pragma unroll
        for (int k = 0; k < 25; ++k) {
            int w = k * 64 + lane;       // 0..1599
            int c = w / 50;
            int l = w - c * 50;
            st[k] = l;
            tt[k] = c * 32 + 31;
            cidx[k] = c * 50 + l;
        }
        for (int j = 0; j < 32; ++j) {
#pragma unroll
            for (int k = 0; k < 25; ++k) {
                st[k] = lptr[(st[k] << 10) + tt[k]];
                tt[k] -= 1;
            }
        }
#pragma unroll
        for (int k = 0; k < 25; ++k) maps[cidx[k]] = (u8)st[k];
    }
    __syncthreads();

    const int idx = idx_ws[b];

    // phase 2: compose chunk maps sequentially
    if (lane == 0) {
        int i = idx;
        for (int c = 31; c >= 0; --c) {
            entries[c + 1] = i;
            i = maps[c * 50 + i];
        }
        entries[0] = i;
    }
    __syncthreads();

    // phase 3: re-walk all 32 chunks in parallel, writing the path
    float* po = out_paths + (size_t)b * TT;
    if (lane < 32) {
        const int c = lane;
        int s = entries[c + 1];
        for (int j = 0; j < 32; ++j) {
            int t = c * 32 + 31 - j;
            int ni = lptr[(s << 10) + t];
            if (t > 0) po[t - 1] = (float)ni;   // paths[t-1] = back_seq[t]
            s = ni;
        }
    }
    if (lane == 0) po[TT - 1] = (float)idx;     // paths[T-1] = argmax(vit)
}

extern "C" void kernel_launch(void* const* d_in, const int* in_sizes, int n_in,
                              void* d_out, int out_size, void* d_ws, size_t ws_size,
                              hipStream_t stream) {
    const float* feats = (const float*)d_in[0];
    const int*   lens  = (const int*)d_in[1];
    const float* trans = (const float*)d_in[2];

    float* scores = (float*)d_out;          // [512]
    float* paths  = scores + BB;            // [512*1024] ints as floats

    int* idx_ws = (int*)d_ws;
    u8*  ptr_ws = (u8*)d_ws + 4096;

    viterbi_fwd<<<BB, 64, 0, stream>>>(feats, lens, trans, scores, idx_ws, ptr_ws);
    viterbi_bwd<<<BB, 64, 0, stream>>>(idx_ws, ptr_ws, paths);
}